// Round 9
// baseline (109.181 us; speedup 1.0000x reference)
//
#include <hip/hip_runtime.h>

typedef unsigned short u16;
typedef unsigned int   u32;
typedef __attribute__((ext_vector_type(8)))  __bf16 bf16x8;
typedef __attribute__((ext_vector_type(16))) float  f32x16;
typedef __attribute__((ext_vector_type(4)))  float  fl4;
typedef __attribute__((ext_vector_type(4)))  u16    u16x4;
typedef __attribute__((ext_vector_type(4)))  u32    u32x4;

#define NB 16
#define NT 2048
#define NC 1024
#define ND 128

// Fragment-order layouts:
//   q/k per batch: [t32 0..63][ds 0..7][lane][8]  (1KB per (t32,ds))
//   v  per batch: [c=t>>4 0..127][dt=d>>5 0..3][lane=(d&31)+32*((t>>3)&1)][j=t&7]
//   wf: [cb 0..11][ks 0..63][lane][8] : W_{cb>>2}[k=ks*16+(lane>>5)*8+j][(cb&3)*32+(lane&31)]

__device__ __forceinline__ u16 f2bf(float f) {
  u32 u = __builtin_bit_cast(u32, f);
  u = (u + 0x7fffu + ((u >> 16) & 1u)) >> 16;
  return (u16)u;
}

__device__ __forceinline__ u32 pk2(float lo, float hi) {
  return (u32)f2bf(lo) | ((u32)f2bf(hi) << 16);
}

// -------------------- Kernel 0: W -> fragment-order wf --------------------
__global__ __launch_bounds__(256) void wprep_k(
    const float* __restrict__ Wq, const float* __restrict__ Wk,
    const float* __restrict__ Wv, u16* __restrict__ wf)
{
  const int cb   = blockIdx.x;          // 0..11
  const int kind = cb >> 2;
  const float* __restrict__ W = (kind == 0) ? Wq : (kind == 1) ? Wk : Wv;
  const int lane = threadIdx.x & 63;
  const int ksq  = threadIdx.x >> 6;    // 0..3
  const int l31 = lane & 31, hi = lane >> 5;
  const int d = (cb & 3) * 32 + l31;
  u16* __restrict__ o = wf + (size_t)cb * 64 * 512;
  #pragma unroll 4
  for (int ii = 0; ii < 16; ++ii) {
    int ks = ksq * 16 + ii;
    int k  = ks * 16 + hi * 8;
    u16x4 p0, p1;
    #pragma unroll
    for (int j = 0; j < 4; ++j) p0[j] = f2bf(W[(size_t)(k + j) * ND + d]);
    #pragma unroll
    for (int j = 0; j < 4; ++j) p1[j] = f2bf(W[(size_t)(k + 4 + j) * ND + d]);
    u16* dst = o + ((size_t)ks * 64 + lane) * 8;
    *(u16x4*)dst = p0;
    *(u16x4*)(dst + 4) = p1;
  }
}

// -------------------- Kernel 1: QKV projection (m97-style, 3 blocks/CU) ----
// 768 blocks x 256 thr; block = 128 rows x one kind (128 cols).
// L = rt + 256*kind -> all 3 kinds of a row-tile on the SAME XCD (x fetched
// once per XCD, then L2 hits). LDS = A single-buffer 16KB, 2 barriers/step.
// A reg-prefetched 1 step ahead; B direct contiguous frag-order global (L2).
__global__ __launch_bounds__(256, 3) void qkv_proj_k(
    const float* __restrict__ x, const u16* __restrict__ wf,
    u16* __restrict__ qf, u16* __restrict__ kf, u16* __restrict__ vf)
{
  const int L    = blockIdx.x;          // 0..767
  const int rt   = L & 255;             // row-tile
  const int kind = L >> 8;              // 0..2
  const int tid  = threadIdx.x;
  const int lane = tid & 63;
  const int wid  = tid >> 6;            // 0..3
  const int wr = wid >> 1, wc = wid & 1;
  const int l31 = lane & 31, hi = lane >> 5;
  const int m0 = rt * 128;

  __shared__ u16 As[128 * 64];          // byte = row*128 + ((2c) ^ ((row&7)<<4))

  // A staging: row = (tid>>4)+it*16, f32 col = (tid&15)*4  (coalesced 256B/row)
  const int srow = tid >> 4;
  const int sc4  = (tid & 15) * 4;
  const float* __restrict__ xr = x + (size_t)(m0 + srow) * NC + sc4;

  fl4 pA[8];
  auto issueA = [&](int k0) {
    #pragma unroll
    for (int it = 0; it < 8; ++it)
      pA[it] = *(const fl4*)(xr + (size_t)it * 16 * NC + k0);
  };
  auto writeA = [&]() {
    char* b = (char*)As;
    #pragma unroll
    for (int it = 0; it < 8; ++it) {
      int row = it * 16 + srow;
      u16x4 pk;
      pk[0] = __builtin_bit_cast(u16, (__bf16)pA[it][0]);
      pk[1] = __builtin_bit_cast(u16, (__bf16)pA[it][1]);
      pk[2] = __builtin_bit_cast(u16, (__bf16)pA[it][2]);
      pk[3] = __builtin_bit_cast(u16, (__bf16)pA[it][3]);
      *(u16x4*)(b + row * 128 + ((sc4 * 2) ^ ((row & 7) << 4))) = pk;
    }
  };

  // wave's B base: col-blocks wc*2 + {0,1} of this kind
  const u16* __restrict__ wfb = wf + ((size_t)(kind * 4 + wc * 2) * 64) * 512 + lane * 8;

  f32x16 acc[2][2] = {};

  issueA(0);
  for (int k = 0; k < 16; ++k) {
    writeA();                            // A(k): regs -> LDS (swizzled)
    if (k < 15) issueA((k + 1) * 64);    // next A loads (land during compute)
    __syncthreads();                     // drain -> A visible (other blocks cover)

    bf16x8 bfr[2][4];
    #pragma unroll
    for (int cb = 0; cb < 2; ++cb)
      #pragma unroll
      for (int ks = 0; ks < 4; ++ks)
        bfr[cb][ks] = *(const bf16x8*)(wfb + ((size_t)cb * 64 + k * 4 + ks) * 512);

    const char* ab = (const char*)As;
    #pragma unroll
    for (int ks = 0; ks < 4; ++ks) {
      #pragma unroll
      for (int fm = 0; fm < 2; ++fm) {
        int row = wr * 64 + fm * 32 + l31;
        bf16x8 a = *(const bf16x8*)(ab + row * 128 + ((ks * 32 + hi * 16) ^ ((row & 7) << 4)));
        #pragma unroll
        for (int cb = 0; cb < 2; ++cb)
          acc[fm][cb] = __builtin_amdgcn_mfma_f32_32x32x16_bf16(a, bfr[cb][ks], acc[fm][cb], 0, 0, 0);
      }
    }
    __syncthreads();                     // readers done before next writeA
  }

  // ---- epilogue: frag-order outputs ----
  #pragma unroll
  for (int fm = 0; fm < 2; ++fm) {
    const int t32 = rt * 4 + wr * 2 + fm;
    #pragma unroll
    for (int cb = 0; cb < 2; ++cb) {
      const int d = wc * 64 + cb * 32 + l31;
      if (kind < 2) {
        u16* __restrict__ o = kind ? kf : qf;
        const float sc = kind ? 1.0f : 0.12752539240377073f; // log2e/sqrt(128)
        const int ds = d >> 4, b3 = (d >> 3) & 1, j = d & 7;
        u16* __restrict__ base = o + ((size_t)t32 * 8 + ds) * 512 + 32 * b3 * 8 + j;
        #pragma unroll
        for (int r = 0; r < 16; ++r) {
          int crow = (r & 3) + 8 * (r >> 2) + 4 * hi;
          base[crow * 8] = f2bf(acc[fm][cb][r] * sc);
        }
      } else {
        const int dt = d >> 5;
        #pragma unroll
        for (int g = 0; g < 4; ++g) {
          int c16   = t32 * 2 + (g >> 1);
          int lanep = l31 + 32 * (g & 1);
          u16x4 pk;
          #pragma unroll
          for (int jj = 0; jj < 4; ++jj) pk[jj] = f2bf(acc[fm][cb][g * 4 + jj]);
          *(u16x4*)(vf + (((size_t)c16 * 4 + dt) * 64 + lanep) * 8 + 4 * hi) = pk;
        }
      }
    }
  }
}

// -------------------- Kernel 2: flash attention (KV-split x2) --------------------
// 1024 blocks x 2 waves; both waves share one (batch, 32-row q-tile), wave w
// handles kv steps s == w (mod 2). Partials merged via LDS (flash combine).
__global__ __launch_bounds__(128, 2) void attn_fwd_k(
    const u16* __restrict__ qw, const u16* __restrict__ kw,
    const u16* __restrict__ vw, float* __restrict__ out)
{
  const int tid  = threadIdx.x;
  const int lane = tid & 63;
  const int w    = tid >> 6;            // 0/1 split
  const int l31  = lane & 31;
  const int hi   = lane >> 5;

  const int c  = blockIdx.x;
  const int bb = (c >> 6) & 15;
  const int qi = ((c & 63) + ((c >> 8) << 4)) & 63;
  const int q0 = qi * 32;
  const int qrow = q0 + l31;

  const u16* __restrict__ qb = qw + ((size_t)bb * 64 + qi) * 4096;
  const u16* __restrict__ kb = kw + (size_t)bb * 64 * 4096;
  const u16* __restrict__ vb = vw + (size_t)bb * 128 * 2048;

  __shared__ float ofs[64][64];         // [dt*16+r][lane]
  __shared__ float mls[2][64];

  bf16x8 qfr[8];
  #pragma unroll
  for (int s = 0; s < 8; ++s)
    qfr[s] = *(const bf16x8*)(qb + ((size_t)s * 64 + lane) * 8);

  f32x16 of[4] = {};
  float m_run = -__builtin_inff();
  float l_run = 0.f;

  const int nsteps = (qi >> 1) + 1;
  for (int s = w; s < nsteps; s += 2) {
    const int kv0 = s * 64;
    const bool masked = (s == nsteps - 1);

    bf16x8 kf0[8], kf1[8];
    #pragma unroll
    for (int t = 0; t < 8; ++t) {
      kf0[t] = *(const bf16x8*)(kb + (((size_t)(2 * s) * 8 + t) * 64 + lane) * 8);
      kf1[t] = *(const bf16x8*)(kb + (((size_t)(2 * s + 1) * 8 + t) * 64 + lane) * 8);
    }
    f32x16 st0 = {}, st1 = {};
    #pragma unroll
    for (int t = 0; t < 8; ++t) {
      st0 = __builtin_amdgcn_mfma_f32_32x32x16_bf16(kf0[t], qfr[t], st0, 0, 0, 0);
      st1 = __builtin_amdgcn_mfma_f32_32x32x16_bf16(kf1[t], qfr[t], st1, 0, 0, 0);
    }
    bf16x8 vfr[4][4];
    #pragma unroll
    for (int ks = 0; ks < 4; ++ks)
      #pragma unroll
      for (int dt = 0; dt < 4; ++dt)
        vfr[dt][ks] = *(const bf16x8*)(vb + (((size_t)((kv0 >> 4) + ks) * 4 + dt) * 64 + lane) * 8);

    if (masked) {
      #pragma unroll
      for (int r = 0; r < 16; ++r) {
        int crow = (r & 3) + 8 * (r >> 2) + 4 * hi;
        st0[r] = (kv0 + crow      <= qrow) ? st0[r] : -1e30f;
        st1[r] = (kv0 + 32 + crow <= qrow) ? st1[r] : -1e30f;
      }
    }

    float pmax = -1e30f;
    #pragma unroll
    for (int r = 0; r < 16; ++r) pmax = fmaxf(pmax, fmaxf(st0[r], st1[r]));
    pmax = fmaxf(pmax, __shfl_xor(pmax, 32, 64));

    const bool no_rescale = (pmax <= m_run);
    const float m_new = fmaxf(m_run, pmax);
    const float fac = __builtin_amdgcn_exp2f(m_run - m_new);
    float rsum = 0.f;
    #pragma unroll
    for (int r = 0; r < 16; ++r) {
      st0[r] = __builtin_amdgcn_exp2f(st0[r] - m_new);
      st1[r] = __builtin_amdgcn_exp2f(st1[r] - m_new);
      rsum += st0[r] + st1[r];
    }
    rsum += __shfl_xor(rsum, 32, 64);
    l_run = l_run * fac + rsum;
    m_run = m_new;

    if (!__all(no_rescale)) {
      #pragma unroll
      for (int r = 0; r < 16; ++r) {
        float fr = __shfl(fac, (r & 3) + 8 * (r >> 2) + 4 * hi, 64);
        #pragma unroll
        for (int dt = 0; dt < 4; ++dt) of[dt][r] *= fr;
      }
    }

    u32x4 pa[4];
    #pragma unroll
    for (int g = 0; g < 4; ++g) {
      const float* sp = (g < 2) ? (const float*)&st0 : (const float*)&st1;
      const int o8 = (g & 1) * 8;
      u32 a0 = pk2(sp[o8 + 0], sp[o8 + 1]);
      u32 a1 = pk2(sp[o8 + 2], sp[o8 + 3]);
      u32 b0 = pk2(sp[o8 + 4], sp[o8 + 5]);
      u32 b1 = pk2(sp[o8 + 6], sp[o8 + 7]);
      u32 ta0 = __shfl_xor(a0, 32, 64);
      u32 ta1 = __shfl_xor(a1, 32, 64);
      u32 tb0 = __shfl_xor(b0, 32, 64);
      u32 tb1 = __shfl_xor(b1, 32, 64);
      pa[g][0] = hi ? tb0 : a0;
      pa[g][1] = hi ? tb1 : a1;
      pa[g][2] = hi ? b0  : ta0;
      pa[g][3] = hi ? b1  : ta1;
    }

    #pragma unroll
    for (int ks = 0; ks < 4; ++ks) {
      bf16x8 paf = __builtin_bit_cast(bf16x8, pa[ks]);
      #pragma unroll
      for (int dt = 0; dt < 4; ++dt)
        of[dt] = __builtin_amdgcn_mfma_f32_32x32x16_bf16(paf, vfr[dt][ks], of[dt], 0, 0, 0);
    }
  }

  if (w == 1) {
    #pragma unroll
    for (int dt = 0; dt < 4; ++dt)
      #pragma unroll
      for (int r = 0; r < 16; ++r)
        ofs[dt * 16 + r][lane] = of[dt][r];
    mls[0][lane] = m_run;
    mls[1][lane] = l_run;
  }
  __syncthreads();
  if (w == 0) {
    const float m1 = mls[0][l31];
    const float l1 = mls[1][l31];
    const float mt = fmaxf(m_run, m1);
    const float f0 = __builtin_amdgcn_exp2f(m_run - mt);
    const float f1 = __builtin_amdgcn_exp2f(m1 - mt);
    const float lt = l_run * f0 + l1 * f1;
    const float rl = 1.0f / lt;
    #pragma unroll
    for (int r = 0; r < 16; ++r) {
      int crow = (r & 3) + 8 * (r >> 2) + 4 * hi;
      float f0r = __shfl(f0, crow, 64);
      float f1r = __shfl(f1, crow, 64);
      float lr  = __shfl(rl, crow, 64);
      #pragma unroll
      for (int dt = 0; dt < 4; ++dt)
        out[((size_t)(bb * NT + q0 + crow)) * ND + dt * 32 + l31] =
            (of[dt][r] * f0r + ofs[dt * 16 + r][lane] * f1r) * lr;
    }
  }
}

extern "C" void kernel_launch(void* const* d_in, const int* in_sizes, int n_in,
                              void* d_out, int out_size, void* d_ws, size_t ws_size,
                              hipStream_t stream) {
  (void)in_sizes; (void)n_in; (void)out_size; (void)ws_size;
  const float* x  = (const float*)d_in[0];
  const float* Wq = (const float*)d_in[1];
  const float* Wk = (const float*)d_in[2];
  const float* Wv = (const float*)d_in[3];
  float* out = (float*)d_out;

  u16* qws = (u16*)d_ws;                                // frag-order q: 8 MB
  u16* kws = qws + (size_t)NB * NT * ND;                // frag-order k: 8 MB
  u16* vws = kws + (size_t)NB * NT * ND;                // frag-order v: 8 MB
  u16* wfs = vws + (size_t)NB * NT * ND;                // frag-order W: 768 KB

  wprep_k<<<dim3(12), dim3(256), 0, stream>>>(Wq, Wk, Wv, wfs);
  qkv_proj_k<<<dim3(768), dim3(256), 0, stream>>>(x, wfs, qws, kws, vws);
  attn_fwd_k<<<dim3(1024), dim3(128), 0, stream>>>(qws, kws, vws, out);
}